// Round 10
// baseline (217.265 us; speedup 1.0000x reference)
//
#include <hip/hip_runtime.h>
#include <hip/hip_bf16.h>
#include <cmath>

// B=1, C=192, D=H=W=16 (4096 pos), 6 heads x hd=32, kernel 5 -> 125 neighbors.
// hid=384, mlp_h=768. fp32 in/out; GEMMs bf16-MFMA fp32-accum, LDS-staged.
// Attention: q fp32 [pos][192] (pre-scaled); K|V fp32 interleaved [pos][384];
// 32 lanes per (pos,head) = 4 subgroups x 8 lanes; no-max softmax; add-merge.
// 8 dispatches: prep | convx | qkv | attn | proj(+stats2) | convx2 | mlp1 | mlp2(splitK)

#define NPOS 4096
#define C_CH 192

typedef __bf16 bf16x8 __attribute__((ext_vector_type(8)));
typedef __bf16 bf16x4 __attribute__((ext_vector_type(4)));
typedef float  f32x4  __attribute__((ext_vector_type(4)));

// ---------------------------------------------------------------------------
// prep kernel: blocks [0,432) convert the 4 weight matrices fp32->bf16;
// blocks [432,624) per-channel sum/sumsq of x; block 432 also zeroes stats2.
// ---------------------------------------------------------------------------
__global__ __launch_bounds__(256) void prep_kernel(
    const float* __restrict__ s0, const float* __restrict__ s1,
    const float* __restrict__ s2, const float* __restrict__ s3,
    __bf16* __restrict__ d0, __bf16* __restrict__ d1,
    __bf16* __restrict__ d2, __bf16* __restrict__ d3,
    const float* __restrict__ x, float* __restrict__ sums, float* __restrict__ sumsq,
    float* __restrict__ stats2zero)
{
    int b = blockIdx.x;
    if (b < 432) {
        const float* src; __bf16* dst; int base;
        if (b < 108)      { src = s0; dst = d0; base = b; }
        else if (b < 144) { src = s1; dst = d1; base = b - 108; }
        else if (b < 288) { src = s2; dst = d2; base = b - 144; }
        else              { src = s3; dst = d3; base = b - 288; }
        int i = (base * 256 + threadIdx.x) * 4;
        float4 v = *(const float4*)(src + i);
        bf16x4 o = { (__bf16)v.x, (__bf16)v.y, (__bf16)v.z, (__bf16)v.w };
        *(bf16x4*)(dst + i) = o;
        return;
    }
    int c = b - 432;
    if (c == 0) {
        for (int i = threadIdx.x; i < 384; i += 256) stats2zero[i] = 0.0f;
    }
    const float4* xc = (const float4*)(x + (size_t)c * NPOS);
    float a = 0.f, a2 = 0.f;
    for (int i = threadIdx.x; i < NPOS / 4; i += 256) {
        float4 v = xc[i];
        a  += v.x + v.y + v.z + v.w;
        a2 += v.x * v.x + v.y * v.y + v.z * v.z + v.w * v.w;
    }
    #pragma unroll
    for (int off = 32; off > 0; off >>= 1) {
        a  += __shfl_down(a, off);
        a2 += __shfl_down(a2, off);
    }
    __shared__ float ls[4], ls2[4];
    int wid = threadIdx.x >> 6;
    if ((threadIdx.x & 63) == 0) { ls[wid] = a; ls2[wid] = a2; }
    __syncthreads();
    if (threadIdx.x == 0) {
        float t = 0.f, t2 = 0.f;
        #pragma unroll
        for (int w = 0; w < 4; w++) { t += ls[w]; t2 += ls2[w]; }
        sums[c] = t; sumsq[c] = t2;
    }
}

// ---------------------------------------------------------------------------
// convx: xb[pos][192] = bf16(x[c][pos] * gs[c]); gamma-MLP computed inline
// per block (redundant but tiny: ~150K MAC).
// ---------------------------------------------------------------------------
__global__ __launch_bounds__(256) void convx_kernel(
    const float* __restrict__ x,
    const float* __restrict__ sums, const float* __restrict__ sumsq,
    const float* __restrict__ scale,
    const float* __restrict__ w1, const float* __restrict__ b1,
    const float* __restrict__ w2, const float* __restrict__ b2,
    __bf16* __restrict__ xb)
{
    __shared__ float stats[C_CH];
    __shared__ float h[384];
    __shared__ float gsl[C_CH];
    __shared__ float lds[192 * 65];
    int t = threadIdx.x;

    if (t < C_CH) stats[t] = sums[t] * (1.0f / (float)NPOS);
    __syncthreads();
    for (int j = t; j < 384; j += 256) {
        float acc = b1[j];
        const float* wr = w1 + (size_t)j * C_CH;
        #pragma unroll 4
        for (int c = 0; c < C_CH; c += 4) {
            float4 w4 = *(const float4*)(wr + c);
            acc += w4.x * stats[c] + w4.y * stats[c + 1] + w4.z * stats[c + 2] + w4.w * stats[c + 3];
        }
        h[j] = fmaxf(acc, 0.0f);
    }
    __syncthreads();
    if (t < C_CH) {
        float acc = b2[t];
        const float* wr = w2 + (size_t)t * 384;
        #pragma unroll 4
        for (int j = 0; j < 384; j += 4) {
            float4 w4 = *(const float4*)(wr + j);
            acc += w4.x * h[j] + w4.y * h[j + 1] + w4.z * h[j + 2] + w4.w * h[j + 3];
        }
        float g = 1.0f / (1.0f + __expf(-acc));
        float rms = sqrtf(sumsq[t] * (1.0f / (float)NPOS) + 1e-6f);
        gsl[t] = scale[t] * g / rms;
    }
    __syncthreads();

    int p0 = blockIdx.x * 64;
    for (int idx = t; idx < 192 * 16; idx += 256) {
        int row = idx >> 4, p4 = idx & 15;
        float4 v = *(const float4*)(x + (size_t)row * NPOS + p0 + p4 * 4);
        float g = gsl[row];
        lds[row * 65 + p4 * 4 + 0] = v.x * g;
        lds[row * 65 + p4 * 4 + 1] = v.y * g;
        lds[row * 65 + p4 * 4 + 2] = v.z * g;
        lds[row * 65 + p4 * 4 + 3] = v.w * g;
    }
    __syncthreads();
    for (int idx = t; idx < 48 * 64; idx += 256) {
        int c4 = idx >> 6, p = idx & 63;
        bf16x4 o;
        #pragma unroll
        for (int j = 0; j < 4; j++) o[j] = (__bf16)lds[(c4 * 4 + j) * 65 + p];
        *(bf16x4*)(xb + (size_t)(p0 + p) * 192 + c4 * 4) = o;
    }
}

// ---------------------------------------------------------------------------
// LDS-staged MFMA GEMM: out[M][4096] = W[M][K] @ X^T, X stored [4096][K] bf16.
// Block 64Mx64N, 256 thr = 2x2 waves, wave 32Mx32N (acc 2x2). K-loop:
// 4 ds_read_b128 + 4 MFMA per k32-step, zero global loads.
//   EPI 0: qkv scatter -> q fp32 [pos][192] (x 1/sqrt(32)), kv fp32 [pos][384]
//   EPI 2: out fp32 [M][4096] = acc+bias+resid; fused per-channel sum/sumsq
//          (wave shfl-reduce + atomics into out_sums/out_sumsq)
//   EPI 3: out bf16 [4096][M] = gelu(acc + bias)
//   EPI 4: split-K accumulate: atomicAdd(out, acc (+bias iff blockIdx.z==0));
//          panel k-range = [blockIdx.z*192, +192)
// ---------------------------------------------------------------------------
template <int K, int EPI>
__global__ __launch_bounds__(256) void gemm_lds(
    const __bf16* __restrict__ W, const float* __restrict__ bias,
    const __bf16* __restrict__ X, void* __restrict__ out,
    const float* __restrict__ resid, int M,
    float* __restrict__ out_kv,
    float* __restrict__ out_sums, float* __restrict__ out_sumsq)
{
    constexpr int KC  = 192;
    constexpr int LDA = 200;   // padded row stride (bf16); 400B -> 2-way-free banks
    __shared__ __bf16 al[64 * LDA];
    __shared__ __bf16 bl[64 * LDA];
    int t    = threadIdx.x;
    int lane = t & 63;
    int wv   = t >> 6;
    int r16  = lane & 15;
    int quad = lane >> 4;
    int wvm  = wv >> 1;
    int wvn  = wv & 1;
    int mBase = blockIdx.y * 64;
    int nBase = blockIdx.x * 64;

    f32x4 acc[2][2];
    #pragma unroll
    for (int i = 0; i < 2; i++)
        #pragma unroll
        for (int j = 0; j < 2; j++)
            acc[i][j] = (f32x4){0.f, 0.f, 0.f, 0.f};

    int kBeg = (EPI == 4) ? blockIdx.z * 192 : 0;
    int kEnd = (EPI == 4) ? kBeg + 192 : K;

    for (int k0 = kBeg; k0 < kEnd; k0 += KC) {
        #pragma unroll
        for (int it = 0; it < 6; it++) {
            int c = it * 256 + t;
            int row = c / 24, off = c - row * 24;
            bf16x8 va = *(const bf16x8*)(W + (size_t)(mBase + row) * K + k0 + off * 8);
            *(bf16x8*)(al + row * LDA + off * 8) = va;
            bf16x8 vb = *(const bf16x8*)(X + (size_t)(nBase + row) * K + k0 + off * 8);
            *(bf16x8*)(bl + row * LDA + off * 8) = vb;
        }
        __syncthreads();
        #pragma unroll
        for (int ks = 0; ks < KC / 32; ks++) {
            bf16x8 a0 = *(const bf16x8*)(al + (wvm * 32 + r16) * LDA + ks * 32 + quad * 8);
            bf16x8 a1 = *(const bf16x8*)(al + (wvm * 32 + 16 + r16) * LDA + ks * 32 + quad * 8);
            bf16x8 b0 = *(const bf16x8*)(bl + (wvn * 32 + r16) * LDA + ks * 32 + quad * 8);
            bf16x8 b1 = *(const bf16x8*)(bl + (wvn * 32 + 16 + r16) * LDA + ks * 32 + quad * 8);
            acc[0][0] = __builtin_amdgcn_mfma_f32_16x16x32_bf16(a0, b0, acc[0][0], 0, 0, 0);
            acc[0][1] = __builtin_amdgcn_mfma_f32_16x16x32_bf16(a0, b1, acc[0][1], 0, 0, 0);
            acc[1][0] = __builtin_amdgcn_mfma_f32_16x16x32_bf16(a1, b0, acc[1][0], 0, 0, 0);
            acc[1][1] = __builtin_amdgcn_mfma_f32_16x16x32_bf16(a1, b1, acc[1][1], 0, 0, 0);
        }
        __syncthreads();
    }

    float sv[2][4], sq[2][4];
    if (EPI == 2) {
        #pragma unroll
        for (int rt = 0; rt < 2; rt++)
            #pragma unroll
            for (int j = 0; j < 4; j++) { sv[rt][j] = 0.f; sq[rt][j] = 0.f; }
    }

    #pragma unroll
    for (int rt = 0; rt < 2; rt++) {
        int m0 = mBase + wvm * 32 + rt * 16 + quad * 4;   // 4 consecutive rows
        float b0, b1, b2, b3;
        if (EPI == 4) {
            bool z0 = (blockIdx.z == 0);
            b0 = z0 ? bias[m0] : 0.f;     b1 = z0 ? bias[m0 + 1] : 0.f;
            b2 = z0 ? bias[m0 + 2] : 0.f; b3 = z0 ? bias[m0 + 3] : 0.f;
        } else {
            b0 = bias[m0]; b1 = bias[m0 + 1]; b2 = bias[m0 + 2]; b3 = bias[m0 + 3];
        }
        #pragma unroll
        for (int ct = 0; ct < 2; ct++) {
            int n = nBase + wvn * 32 + ct * 16 + r16;
            f32x4 a4 = acc[rt][ct];
            float g0 = a4[0] + b0, g1 = a4[1] + b1, g2 = a4[2] + b2, g3 = a4[3] + b3;
            if (EPI == 0) {
                int sect = m0 / 192;          // block fully inside one section
                int o0 = m0 - sect * 192;
                if (sect == 0) {
                    const float qs = 0.17677669529663687f;   // 32^-0.5 folded into q
                    *(float4*)((float*)out + (size_t)n * 192 + o0) =
                        make_float4(g0 * qs, g1 * qs, g2 * qs, g3 * qs);
                } else {
                    *(float4*)(out_kv + (size_t)n * 384 + (sect - 1) * 192 + o0) =
                        make_float4(g0, g1, g2, g3);
                }
            } else if (EPI == 2) {
                float* o = (float*)out;
                size_t i0 = (size_t)m0 * NPOS + n;
                float v0 = g0 + resid[i0];
                float v1 = g1 + resid[i0 + NPOS];
                float v2 = g2 + resid[i0 + 2 * NPOS];
                float v3 = g3 + resid[i0 + 3 * NPOS];
                o[i0] = v0; o[i0 + NPOS] = v1; o[i0 + 2 * NPOS] = v2; o[i0 + 3 * NPOS] = v3;
                sv[rt][0] += v0; sq[rt][0] += v0 * v0;
                sv[rt][1] += v1; sq[rt][1] += v1 * v1;
                sv[rt][2] += v2; sq[rt][2] += v2 * v2;
                sv[rt][3] += v3; sq[rt][3] += v3 * v3;
            } else if (EPI == 4) {
                float* o = (float*)out;
                size_t i0 = (size_t)m0 * NPOS + n;
                atomicAdd(o + i0, g0);
                atomicAdd(o + i0 + NPOS, g1);
                atomicAdd(o + i0 + 2 * NPOS, g2);
                atomicAdd(o + i0 + 3 * NPOS, g3);
            } else {
                bf16x4 v;
                v[0] = (__bf16)(0.5f * g0 * (1.0f + erff(g0 * 0.7071067811865475f)));
                v[1] = (__bf16)(0.5f * g1 * (1.0f + erff(g1 * 0.7071067811865475f)));
                v[2] = (__bf16)(0.5f * g2 * (1.0f + erff(g2 * 0.7071067811865475f)));
                v[3] = (__bf16)(0.5f * g3 * (1.0f + erff(g3 * 0.7071067811865475f)));
                *(bf16x4*)((__bf16*)out + (size_t)n * M + m0) = v;
            }
        }
    }

    if (EPI == 2) {
        // wave-reduce over the 16 r16 lanes (shfl_xor 1/2/4/8 stay in-quad-group)
        #pragma unroll
        for (int rt = 0; rt < 2; rt++) {
            #pragma unroll
            for (int j = 0; j < 4; j++) {
                float a = sv[rt][j], b = sq[rt][j];
                a += __shfl_xor(a, 1); a += __shfl_xor(a, 2);
                a += __shfl_xor(a, 4); a += __shfl_xor(a, 8);
                b += __shfl_xor(b, 1); b += __shfl_xor(b, 2);
                b += __shfl_xor(b, 4); b += __shfl_xor(b, 8);
                if (r16 == 0) {
                    int m = mBase + wvm * 32 + rt * 16 + quad * 4 + j;
                    atomicAdd(out_sums + m, a);
                    atomicAdd(out_sumsq + m, b);
                }
            }
        }
    }
}

// ---------------------------------------------------------------------------
// Neighborhood attention: 32 lanes per (pos,head) = 4 subgroups x 8 lanes.
// K|V fp32 interleaved [pos][384]; row-walk addressing; no-max softmax
// (scores O(0.1) by construction); disjoint-set add-merge.
// ---------------------------------------------------------------------------
__global__ __launch_bounds__(256) void attn_kernel(
    const float* __restrict__ q, const float* __restrict__ kv, __bf16* __restrict__ o)
{
    int t = threadIdx.x;
    int pairIdx = blockIdx.x * 8 + (t >> 5);    // 8 pairs per 256-thread block
    int sg   = (t >> 3) & 3;                    // subgroup 0..3
    int lane = t & 7;                           // channel group within subgroup
    int pos = pairIdx / 6;
    int head = pairIdx - pos * 6;
    int wq = pos & 15;
    int hq = (pos >> 4) & 15;
    int dq = pos >> 8;
    int d0 = min(max(dq - 2, 0), 11);
    int h0 = min(max(hq - 2, 0), 11);
    int w0 = min(max(wq - 2, 0), 11);

    const float* kvb = kv + head * 32 + lane * 4;
    float4 q4 = *(const float4*)(q + (size_t)pos * 192 + head * 32 + lane * 4);

    float l = 0.0f;
    float4 acc = make_float4(0.f, 0.f, 0.f, 0.f);

    for (int dh = sg; dh < 25; dh += 4) {
        int di = dh / 5;
        int hi = dh - di * 5;
        int np0 = (d0 + di) * 256 + (h0 + hi) * 16 + w0;
        const float* p = kvb + (size_t)np0 * 384;
        #pragma unroll
        for (int wi = 0; wi < 5; wi++) {
            float4 k4 = *(const float4*)p;
            float4 v4 = *(const float4*)(p + 192);
            float s = q4.x * k4.x + q4.y * k4.y + q4.z * k4.z + q4.w * k4.w;
            s += __shfl_xor(s, 1);
            s += __shfl_xor(s, 2);
            s += __shfl_xor(s, 4);
            float pr = __expf(s);       // q pre-scaled by 32^-0.5
            l += pr;
            acc.x += pr * v4.x;
            acc.y += pr * v4.y;
            acc.z += pr * v4.z;
            acc.w += pr * v4.w;
            p += 384;
        }
    }

    #pragma unroll
    for (int off = 8; off <= 16; off <<= 1) {
        l     += __shfl_xor(l, off);
        acc.x += __shfl_xor(acc.x, off);
        acc.y += __shfl_xor(acc.y, off);
        acc.z += __shfl_xor(acc.z, off);
        acc.w += __shfl_xor(acc.w, off);
    }

    if (sg == 0) {
        float rl = 1.0f / l;
        bf16x4 ov = { (__bf16)(acc.x * rl), (__bf16)(acc.y * rl),
                      (__bf16)(acc.z * rl), (__bf16)(acc.w * rl) };
        *(bf16x4*)(o + (size_t)pos * 192 + head * 32 + lane * 4) = ov;
    }
}

// ---------------------------------------------------------------------------
extern "C" void kernel_launch(void* const* d_in, const int* in_sizes, int n_in,
                              void* d_out, int out_size, void* d_ws, size_t ws_size,
                              hipStream_t stream)
{
    const float* x      = (const float*)d_in[0];
    const float* scale1 = (const float*)d_in[1];
    const float* n1_w1  = (const float*)d_in[2];
    const float* n1_b1  = (const float*)d_in[3];
    const float* n1_w2  = (const float*)d_in[4];
    const float* n1_b2  = (const float*)d_in[5];
    const float* qkv_w  = (const float*)d_in[6];
    const float* qkv_b  = (const float*)d_in[7];
    const float* proj_w = (const float*)d_in[8];
    const float* proj_b = (const float*)d_in[9];
    const float* scale2 = (const float*)d_in[10];
    const float* n2_w1  = (const float*)d_in[11];
    const float* n2_b1  = (const float*)d_in[12];
    const float* n2_w2  = (const float*)d_in[13];
    const float* n2_b2  = (const float*)d_in[14];
    const float* mlp_w1 = (const float*)d_in[15];
    const float* mlp_b1 = (const float*)d_in[16];
    const float* mlp_w2 = (const float*)d_in[17];
    const float* mlp_b2 = (const float*)d_in[18];

    float* ws = (float*)d_ws;
    // ws floats:
    //  [0, 786432)         q fp32 [4096][192] (pre-scaled by 32^-0.5)
    //  [786432, 2359296)   kv fp32 [4096][384] (K | V interleaved per pos)
    //  (q+kv[0:1.5M) aliased by m_buf bf16 [4096][768] after attn)
    //  [2359296, 2752512)  xb bf16 [4096][192]
    //  [2752512, 3145728)  o_attn bf16 [4096][192]
    //  [3145728, 3366912)  weights bf16: qkv|proj|mlp1|mlp2
    //  [3366912, 3367296)  sums | sumsq  (norm1 stats)
    //  [3367296, 3367680)  sums2 | sumsq2 (norm2 stats, zeroed by prep)
    float*  q_buf  = ws;
    float*  kv_buf = ws + 786432;
    __bf16* m_buf  = (__bf16*)ws;
    __bf16* xb     = (__bf16*)(ws + 2359296);
    __bf16* o_attn = (__bf16*)(ws + 2752512);
    __bf16* qkv_wb = (__bf16*)(ws + 3145728);
    __bf16* proj_wb = qkv_wb + 110592;
    __bf16* m1_wb   = proj_wb + 36864;
    __bf16* m2_wb   = m1_wb + 147456;
    float*  sums   = ws + 3366912;
    float*  sumsq  = sums + 192;
    float*  sums2  = ws + 3367296;
    float*  sumsq2 = sums2 + 192;

    float* x2 = (float*)d_out;

    prep_kernel<<<624, 256, 0, stream>>>(qkv_w, proj_w, mlp_w1, mlp_w2,
                                         qkv_wb, proj_wb, m1_wb, m2_wb,
                                         x, sums, sumsq, sums2);
    convx_kernel<<<64, 256, 0, stream>>>(x, sums, sumsq, scale1,
                                         n1_w1, n1_b1, n1_w2, n1_b2, xb);
    gemm_lds<192, 0><<<dim3(64, 9), 256, 0, stream>>>(qkv_wb, qkv_b, xb, (void*)q_buf,
                                                      nullptr, 576, kv_buf, nullptr, nullptr);
    attn_kernel<<<3072, 256, 0, stream>>>(q_buf, kv_buf, o_attn);
    gemm_lds<192, 2><<<dim3(64, 3), 256, 0, stream>>>(proj_wb, proj_b, o_attn, (void*)x2,
                                                      x, 192, nullptr, sums2, sumsq2);
    convx_kernel<<<64, 256, 0, stream>>>(x2, sums2, sumsq2, scale2,
                                         n2_w1, n2_b1, n2_w2, n2_b2, xb);
    gemm_lds<192, 3><<<dim3(64, 12), 256, 0, stream>>>(m1_wb, mlp_b1, xb, (void*)m_buf,
                                                       nullptr, 768, nullptr, nullptr, nullptr);
    gemm_lds<768, 4><<<dim3(64, 3, 4), 256, 0, stream>>>(m2_wb, mlp_b2, m_buf, (void*)x2,
                                                         nullptr, 192, nullptr, nullptr, nullptr);
}

// Round 11
// 199.062 us; speedup vs baseline: 1.0914x; 1.0914x over previous
//
#include <hip/hip_runtime.h>
#include <hip/hip_bf16.h>
#include <cmath>

// B=1, C=192, D=H=W=16 (4096 pos), 6 heads x hd=32, kernel 5 -> 125 neighbors.
// hid=384, mlp_h=768. fp32 in/out; GEMMs bf16-MFMA fp32-accum, LDS-staged.
// Attention: q fp32 [pos][192] (pre-scaled); K|V fp32 interleaved [pos][384];
// 32 lanes per (pos,head) = 4 subgroups x 8 lanes; no-max softmax; add-merge.
// 9 dispatches (R9 structure); convx at 256 blocks (16 pos each).

#define NPOS 4096
#define C_CH 192

typedef __bf16 bf16x8 __attribute__((ext_vector_type(8)));
typedef __bf16 bf16x4 __attribute__((ext_vector_type(4)));
typedef float  f32x4  __attribute__((ext_vector_type(4)));

// ---------------------------------------------------------------------------
// prep kernel: blocks [0,432) convert the 4 weight matrices fp32->bf16;
// blocks [432,624) compute per-channel sum/sumsq of x (stats for norm1).
// ---------------------------------------------------------------------------
__global__ __launch_bounds__(256) void prep_kernel(
    const float* __restrict__ s0, const float* __restrict__ s1,
    const float* __restrict__ s2, const float* __restrict__ s3,
    __bf16* __restrict__ d0, __bf16* __restrict__ d1,
    __bf16* __restrict__ d2, __bf16* __restrict__ d3,
    const float* __restrict__ x, float* __restrict__ sums, float* __restrict__ sumsq)
{
    int b = blockIdx.x;
    if (b < 432) {
        const float* src; __bf16* dst; int base;
        if (b < 108)      { src = s0; dst = d0; base = b; }
        else if (b < 144) { src = s1; dst = d1; base = b - 108; }
        else if (b < 288) { src = s2; dst = d2; base = b - 144; }
        else              { src = s3; dst = d3; base = b - 288; }
        int i = (base * 256 + threadIdx.x) * 4;
        float4 v = *(const float4*)(src + i);
        bf16x4 o = { (__bf16)v.x, (__bf16)v.y, (__bf16)v.z, (__bf16)v.w };
        *(bf16x4*)(dst + i) = o;
        return;
    }
    int c = b - 432;
    const float4* xc = (const float4*)(x + (size_t)c * NPOS);
    float a = 0.f, a2 = 0.f;
    for (int i = threadIdx.x; i < NPOS / 4; i += 256) {
        float4 v = xc[i];
        a  += v.x + v.y + v.z + v.w;
        a2 += v.x * v.x + v.y * v.y + v.z * v.z + v.w * v.w;
    }
    #pragma unroll
    for (int off = 32; off > 0; off >>= 1) {
        a  += __shfl_down(a, off);
        a2 += __shfl_down(a2, off);
    }
    __shared__ float ls[4], ls2[4];
    int wid = threadIdx.x >> 6;
    if ((threadIdx.x & 63) == 0) { ls[wid] = a; ls2[wid] = a2; }
    __syncthreads();
    if (threadIdx.x == 0) {
        float t = 0.f, t2 = 0.f;
        #pragma unroll
        for (int w = 0; w < 4; w++) { t += ls[w]; t2 += ls2[w]; }
        sums[c] = t; sumsq[c] = t2;
    }
}

// ---------------------------------------------------------------------------
// per-channel sum / sumsq (standalone, for norm2 on x2)
// ---------------------------------------------------------------------------
__global__ __launch_bounds__(256) void stats_kernel(
    const float* __restrict__ x, float* __restrict__ sums, float* __restrict__ sumsq)
{
    int c = blockIdx.x;
    const float4* xc = (const float4*)(x + (size_t)c * NPOS);
    float a = 0.f, a2 = 0.f;
    for (int i = threadIdx.x; i < NPOS / 4; i += 256) {
        float4 v = xc[i];
        a  += v.x + v.y + v.z + v.w;
        a2 += v.x * v.x + v.y * v.y + v.z * v.z + v.w * v.w;
    }
    #pragma unroll
    for (int off = 32; off > 0; off >>= 1) {
        a  += __shfl_down(a, off);
        a2 += __shfl_down(a2, off);
    }
    __shared__ float ls[4], ls2[4];
    int wid = threadIdx.x >> 6;
    if ((threadIdx.x & 63) == 0) { ls[wid] = a; ls2[wid] = a2; }
    __syncthreads();
    if (threadIdx.x == 0) {
        float t = 0.f, t2 = 0.f;
        #pragma unroll
        for (int w = 0; w < 4; w++) { t += ls[w]; t2 += ls2[w]; }
        sums[c] = t; sumsq[c] = t2;
    }
}

// ---------------------------------------------------------------------------
// convx: xb[pos][192] = bf16(x[c][pos] * gs[c]); gamma-MLP computed inline
// per block (redundant but tiny). 256 blocks x 16 positions.
// ---------------------------------------------------------------------------
__global__ __launch_bounds__(256) void convx_kernel(
    const float* __restrict__ x,
    const float* __restrict__ sums, const float* __restrict__ sumsq,
    const float* __restrict__ scale,
    const float* __restrict__ w1, const float* __restrict__ b1,
    const float* __restrict__ w2, const float* __restrict__ b2,
    __bf16* __restrict__ xb)
{
    __shared__ float stats[C_CH];
    __shared__ float h[384];
    __shared__ float gsl[C_CH];
    __shared__ float lds[192 * 17];
    int t = threadIdx.x;

    if (t < C_CH) stats[t] = sums[t] * (1.0f / (float)NPOS);
    __syncthreads();
    for (int j = t; j < 384; j += 256) {
        float acc = b1[j];
        const float* wr = w1 + (size_t)j * C_CH;
        #pragma unroll 4
        for (int c = 0; c < C_CH; c += 4) {
            float4 w4 = *(const float4*)(wr + c);
            acc += w4.x * stats[c] + w4.y * stats[c + 1] + w4.z * stats[c + 2] + w4.w * stats[c + 3];
        }
        h[j] = fmaxf(acc, 0.0f);
    }
    __syncthreads();
    if (t < C_CH) {
        float acc = b2[t];
        const float* wr = w2 + (size_t)t * 384;
        #pragma unroll 4
        for (int j = 0; j < 384; j += 4) {
            float4 w4 = *(const float4*)(wr + j);
            acc += w4.x * h[j] + w4.y * h[j + 1] + w4.z * h[j + 2] + w4.w * h[j + 3];
        }
        float g = 1.0f / (1.0f + __expf(-acc));
        float rms = sqrtf(sumsq[t] * (1.0f / (float)NPOS) + 1e-6f);
        gsl[t] = scale[t] * g / rms;
    }
    __syncthreads();

    // 16 positions per block: stage x[c][p0..p0+16) * gs[c] into LDS (stride 17)
    int p0 = blockIdx.x * 16;
    for (int idx = t; idx < 192 * 4; idx += 256) {
        int row = idx >> 2, p4 = idx & 3;
        float4 v = *(const float4*)(x + (size_t)row * NPOS + p0 + p4 * 4);
        float g = gsl[row];
        lds[row * 17 + p4 * 4 + 0] = v.x * g;
        lds[row * 17 + p4 * 4 + 1] = v.y * g;
        lds[row * 17 + p4 * 4 + 2] = v.z * g;
        lds[row * 17 + p4 * 4 + 3] = v.w * g;
    }
    __syncthreads();
    // transpose out: 48 c4-groups x 16 positions = 768 items
    for (int idx = t; idx < 48 * 16; idx += 256) {
        int c4 = idx >> 4, p = idx & 15;
        bf16x4 o;
        #pragma unroll
        for (int j = 0; j < 4; j++) o[j] = (__bf16)lds[(c4 * 4 + j) * 17 + p];
        *(bf16x4*)(xb + (size_t)(p0 + p) * 192 + c4 * 4) = o;
    }
}

// ---------------------------------------------------------------------------
// LDS-staged MFMA GEMM: out[M][4096] = W[M][K] @ X^T, X stored [4096][K] bf16.
// Block 64Mx64N, 256 thr = 2x2 waves, wave 32Mx32N (acc 2x2). K-loop:
// 4 ds_read_b128 + 4 MFMA per k32-step, zero global loads.
//   EPI 0: qkv scatter -> q fp32 [pos][192] (x 1/sqrt(32)), kv fp32 [pos][384]
//   EPI 2: out fp32 [M][4096] = acc + bias + resid
//   EPI 3: out bf16 [4096][M] = gelu(acc + bias)
// ---------------------------------------------------------------------------
template <int K, int EPI>
__global__ __launch_bounds__(256) void gemm_lds(
    const __bf16* __restrict__ W, const float* __restrict__ bias,
    const __bf16* __restrict__ X, void* __restrict__ out,
    const float* __restrict__ resid, int M,
    float* __restrict__ out_kv)
{
    constexpr int KC  = 192;
    constexpr int LDA = 200;   // padded row stride (bf16); 400B -> 2-way-free banks
    __shared__ __bf16 al[64 * LDA];
    __shared__ __bf16 bl[64 * LDA];
    int t    = threadIdx.x;
    int lane = t & 63;
    int wv   = t >> 6;
    int r16  = lane & 15;
    int quad = lane >> 4;
    int wvm  = wv >> 1;
    int wvn  = wv & 1;
    int mBase = blockIdx.y * 64;
    int nBase = blockIdx.x * 64;

    f32x4 acc[2][2];
    #pragma unroll
    for (int i = 0; i < 2; i++)
        #pragma unroll
        for (int j = 0; j < 2; j++)
            acc[i][j] = (f32x4){0.f, 0.f, 0.f, 0.f};

    for (int k0 = 0; k0 < K; k0 += KC) {
        #pragma unroll
        for (int it = 0; it < 6; it++) {
            int c = it * 256 + t;
            int row = c / 24, off = c - row * 24;
            bf16x8 va = *(const bf16x8*)(W + (size_t)(mBase + row) * K + k0 + off * 8);
            *(bf16x8*)(al + row * LDA + off * 8) = va;
            bf16x8 vb = *(const bf16x8*)(X + (size_t)(nBase + row) * K + k0 + off * 8);
            *(bf16x8*)(bl + row * LDA + off * 8) = vb;
        }
        __syncthreads();
        #pragma unroll
        for (int ks = 0; ks < KC / 32; ks++) {
            bf16x8 a0 = *(const bf16x8*)(al + (wvm * 32 + r16) * LDA + ks * 32 + quad * 8);
            bf16x8 a1 = *(const bf16x8*)(al + (wvm * 32 + 16 + r16) * LDA + ks * 32 + quad * 8);
            bf16x8 b0 = *(const bf16x8*)(bl + (wvn * 32 + r16) * LDA + ks * 32 + quad * 8);
            bf16x8 b1 = *(const bf16x8*)(bl + (wvn * 32 + 16 + r16) * LDA + ks * 32 + quad * 8);
            acc[0][0] = __builtin_amdgcn_mfma_f32_16x16x32_bf16(a0, b0, acc[0][0], 0, 0, 0);
            acc[0][1] = __builtin_amdgcn_mfma_f32_16x16x32_bf16(a0, b1, acc[0][1], 0, 0, 0);
            acc[1][0] = __builtin_amdgcn_mfma_f32_16x16x32_bf16(a1, b0, acc[1][0], 0, 0, 0);
            acc[1][1] = __builtin_amdgcn_mfma_f32_16x16x32_bf16(a1, b1, acc[1][1], 0, 0, 0);
        }
        __syncthreads();
    }

    #pragma unroll
    for (int rt = 0; rt < 2; rt++) {
        int m0 = mBase + wvm * 32 + rt * 16 + quad * 4;   // 4 consecutive rows
        float b0 = bias[m0], b1 = bias[m0 + 1], b2 = bias[m0 + 2], b3 = bias[m0 + 3];
        #pragma unroll
        for (int ct = 0; ct < 2; ct++) {
            int n = nBase + wvn * 32 + ct * 16 + r16;
            f32x4 a4 = acc[rt][ct];
            float g0 = a4[0] + b0, g1 = a4[1] + b1, g2 = a4[2] + b2, g3 = a4[3] + b3;
            if (EPI == 0) {
                int sect = m0 / 192;          // block fully inside one section
                int o0 = m0 - sect * 192;
                if (sect == 0) {
                    const float qs = 0.17677669529663687f;   // 32^-0.5 folded into q
                    *(float4*)((float*)out + (size_t)n * 192 + o0) =
                        make_float4(g0 * qs, g1 * qs, g2 * qs, g3 * qs);
                } else {
                    *(float4*)(out_kv + (size_t)n * 384 + (sect - 1) * 192 + o0) =
                        make_float4(g0, g1, g2, g3);
                }
            } else if (EPI == 2) {
                float* o = (float*)out;
                size_t i0 = (size_t)m0 * NPOS + n;
                o[i0]            = g0 + resid[i0];
                o[i0 + NPOS]     = g1 + resid[i0 + NPOS];
                o[i0 + 2 * NPOS] = g2 + resid[i0 + 2 * NPOS];
                o[i0 + 3 * NPOS] = g3 + resid[i0 + 3 * NPOS];
            } else {
                bf16x4 v;
                v[0] = (__bf16)(0.5f * g0 * (1.0f + erff(g0 * 0.7071067811865475f)));
                v[1] = (__bf16)(0.5f * g1 * (1.0f + erff(g1 * 0.7071067811865475f)));
                v[2] = (__bf16)(0.5f * g2 * (1.0f + erff(g2 * 0.7071067811865475f)));
                v[3] = (__bf16)(0.5f * g3 * (1.0f + erff(g3 * 0.7071067811865475f)));
                *(bf16x4*)((__bf16*)out + (size_t)n * M + m0) = v;
            }
        }
    }
}

// ---------------------------------------------------------------------------
// Neighborhood attention: 32 lanes per (pos,head) = 4 subgroups x 8 lanes.
// K|V fp32 interleaved [pos][384]; row-walk addressing; no-max softmax
// (scores O(0.1) by construction); disjoint-set add-merge.
// ---------------------------------------------------------------------------
__global__ __launch_bounds__(256) void attn_kernel(
    const float* __restrict__ q, const float* __restrict__ kv, __bf16* __restrict__ o)
{
    int t = threadIdx.x;
    int pairIdx = blockIdx.x * 8 + (t >> 5);    // 8 pairs per 256-thread block
    int sg   = (t >> 3) & 3;                    // subgroup 0..3
    int lane = t & 7;                           // channel group within subgroup
    int pos = pairIdx / 6;
    int head = pairIdx - pos * 6;
    int wq = pos & 15;
    int hq = (pos >> 4) & 15;
    int dq = pos >> 8;
    int d0 = min(max(dq - 2, 0), 11);
    int h0 = min(max(hq - 2, 0), 11);
    int w0 = min(max(wq - 2, 0), 11);

    const float* kvb = kv + head * 32 + lane * 4;
    float4 q4 = *(const float4*)(q + (size_t)pos * 192 + head * 32 + lane * 4);

    float l = 0.0f;
    float4 acc = make_float4(0.f, 0.f, 0.f, 0.f);

    for (int dh = sg; dh < 25; dh += 4) {
        int di = dh / 5;
        int hi = dh - di * 5;
        int np0 = (d0 + di) * 256 + (h0 + hi) * 16 + w0;
        const float* p = kvb + (size_t)np0 * 384;
        #pragma unroll
        for (int wi = 0; wi < 5; wi++) {
            float4 k4 = *(const float4*)p;
            float4 v4 = *(const float4*)(p + 192);
            float s = q4.x * k4.x + q4.y * k4.y + q4.z * k4.z + q4.w * k4.w;
            s += __shfl_xor(s, 1);
            s += __shfl_xor(s, 2);
            s += __shfl_xor(s, 4);
            float pr = __expf(s);       // q pre-scaled by 32^-0.5
            l += pr;
            acc.x += pr * v4.x;
            acc.y += pr * v4.y;
            acc.z += pr * v4.z;
            acc.w += pr * v4.w;
            p += 384;
        }
    }

    #pragma unroll
    for (int off = 8; off <= 16; off <<= 1) {
        l     += __shfl_xor(l, off);
        acc.x += __shfl_xor(acc.x, off);
        acc.y += __shfl_xor(acc.y, off);
        acc.z += __shfl_xor(acc.z, off);
        acc.w += __shfl_xor(acc.w, off);
    }

    if (sg == 0) {
        float rl = 1.0f / l;
        bf16x4 ov = { (__bf16)(acc.x * rl), (__bf16)(acc.y * rl),
                      (__bf16)(acc.z * rl), (__bf16)(acc.w * rl) };
        *(bf16x4*)(o + (size_t)pos * 192 + head * 32 + lane * 4) = ov;
    }
}

// ---------------------------------------------------------------------------
extern "C" void kernel_launch(void* const* d_in, const int* in_sizes, int n_in,
                              void* d_out, int out_size, void* d_ws, size_t ws_size,
                              hipStream_t stream)
{
    const float* x      = (const float*)d_in[0];
    const float* scale1 = (const float*)d_in[1];
    const float* n1_w1  = (const float*)d_in[2];
    const float* n1_b1  = (const float*)d_in[3];
    const float* n1_w2  = (const float*)d_in[4];
    const float* n1_b2  = (const float*)d_in[5];
    const float* qkv_w  = (const float*)d_in[6];
    const float* qkv_b  = (const float*)d_in[7];
    const float* proj_w = (const float*)d_in[8];
    const float* proj_b = (const float*)d_in[9];
    const float* scale2 = (const float*)d_in[10];
    const float* n2_w1  = (const float*)d_in[11];
    const float* n2_b1  = (const float*)d_in[12];
    const float* n2_w2  = (const float*)d_in[13];
    const float* n2_b2  = (const float*)d_in[14];
    const float* mlp_w1 = (const float*)d_in[15];
    const float* mlp_b1 = (const float*)d_in[16];
    const float* mlp_w2 = (const float*)d_in[17];
    const float* mlp_b2 = (const float*)d_in[18];

    float* ws = (float*)d_ws;
    // ws floats:
    //  [0, 786432)         q fp32 [4096][192] (pre-scaled by 32^-0.5)
    //  [786432, 2359296)   kv fp32 [4096][384] (K | V interleaved per pos)
    //  (q+kv[0:1.5M) aliased by m_buf bf16 [4096][768] after attn)
    //  [2359296, 2752512)  xb bf16 [4096][192]
    //  [2752512, 3145728)  o_attn bf16 [4096][192]
    //  [3145728, 3366912)  weights bf16: qkv|proj|mlp1|mlp2
    //  [3366912, 3367488)  sums | sumsq
    float*  q_buf  = ws;
    float*  kv_buf = ws + 786432;
    __bf16* m_buf  = (__bf16*)ws;
    __bf16* xb     = (__bf16*)(ws + 2359296);
    __bf16* o_attn = (__bf16*)(ws + 2752512);
    __bf16* qkv_wb = (__bf16*)(ws + 3145728);
    __bf16* proj_wb = qkv_wb + 110592;
    __bf16* m1_wb   = proj_wb + 36864;
    __bf16* m2_wb   = m1_wb + 147456;
    float*  sums   = ws + 3366912;
    float*  sumsq  = sums + 192;

    float* x2 = (float*)d_out;

    prep_kernel<<<624, 256, 0, stream>>>(qkv_w, proj_w, mlp_w1, mlp_w2,
                                         qkv_wb, proj_wb, m1_wb, m2_wb,
                                         x, sums, sumsq);
    convx_kernel<<<256, 256, 0, stream>>>(x, sums, sumsq, scale1,
                                          n1_w1, n1_b1, n1_w2, n1_b2, xb);
    gemm_lds<192, 0><<<dim3(64, 9), 256, 0, stream>>>(qkv_wb, qkv_b, xb, (void*)q_buf,
                                                      nullptr, 576, kv_buf);
    attn_kernel<<<3072, 256, 0, stream>>>(q_buf, kv_buf, o_attn);
    gemm_lds<192, 2><<<dim3(64, 3), 256, 0, stream>>>(proj_wb, proj_b, o_attn, (void*)x2,
                                                      x, 192, nullptr);
    stats_kernel<<<192, 256, 0, stream>>>(x2, sums, sumsq);
    convx_kernel<<<256, 256, 0, stream>>>(x2, sums, sumsq, scale2,
                                          n2_w1, n2_b1, n2_w2, n2_b2, xb);
    gemm_lds<192, 3><<<dim3(64, 12), 256, 0, stream>>>(m1_wb, mlp_b1, xb, (void*)m_buf,
                                                       nullptr, 768, nullptr);
    gemm_lds<768, 2><<<dim3(64, 3), 256, 0, stream>>>(m2_wb, mlp_b2, m_buf, (void*)x2,
                                                      x2, 192, nullptr);
}